// Round 9
// baseline (191.249 us; speedup 1.0000x reference)
//
#include <hip/hip_runtime.h>

#define N_NODES  50000
#define N_EDGES  800000
#define N_GRAPHS 512
#define HID      64
#define NCLS     5
#define NB       64      // bucket capacity per node (max deg ~40 for this graph)
#define EST      36      // LDS embed row stride in uints
#define AST      68      // LDS As row stride in uints (64 data + 4 pad)

typedef __attribute__((ext_vector_type(8))) short bf16x8;
typedef __attribute__((ext_vector_type(4))) float f32x4;

__device__ inline unsigned short f2bf(float f) {
    unsigned int u = __builtin_bit_cast(unsigned int, f);
    unsigned int r = (u + 0x7FFFu + ((u >> 16) & 1u)) >> 16;   // RNE
    return (unsigned short)r;
}
__device__ inline unsigned int packbf(float a, float b) {
    return (unsigned int)f2bf(a) | ((unsigned int)f2bf(b) << 16);
}
__device__ inline float bf2f(unsigned int u16) {
    unsigned int t = u16 << 16;
    return __builtin_bit_cast(float, t);
}

// ------- merged prep+fill (R6 form: 8x XCD-range replication + 2-edge ILP) -------
#define XCDS   8
#define NPX    (N_NODES / XCDS)                     // 6250, exact
#define EPB    512                                  // edges per chunk
#define ECH2   ((N_EDGES + EPB - 1) / EPB)          // 1563 chunks
#define SEC_E  (ECH2 * XCDS * 256)                  // 3,201,024 threads
#define EBUF_T (128 * 32)
#define PW_T   (64 * 64)
#define PREP_T (SEC_E + EBUF_T + N_NODES + 2 * PW_T)
__global__ void k_prep_fill(
    const int* __restrict__ src, const int* __restrict__ dst,
    const int* __restrict__ tok,
    int* __restrict__ cnt, unsigned int* __restrict__ bucket,
    const float* __restrict__ embed, unsigned int* __restrict__ ebufg,
    const int* __restrict__ batch,
    int* __restrict__ pos_start, int* __restrict__ pos_end,
    const float* __restrict__ W1l, const float* __restrict__ W1r,
    unsigned int* __restrict__ wb1,
    const float* __restrict__ W2l, const float* __restrict__ W2r,
    unsigned int* __restrict__ wb2) {
    int gid = blockIdx.x * blockDim.x + threadIdx.x;
    if (gid < SEC_E) {
        int blk   = gid >> 8;          // == blockIdx.x within this section
        int tidl  = gid & 255;
        int range = blk & 7;           // XCD slot (round-robin heuristic)
        int chunk = blk >> 3;          // 0..1562
        int lo = range * NPX;
        int e0 = chunk * EPB + tidl;
        int e1 = e0 + 256;
        int d0 = (e0 < N_EDGES) ? dst[e0] : -1;
        int d1 = (e1 < N_EDGES) ? dst[e1] : -1;
        int s0 = (e0 < N_EDGES) ? src[e0] : 0;
        int s1 = (e1 < N_EDGES) ? src[e1] : 0;
        bool k0 = (d0 >= lo) && (d0 < lo + NPX);
        bool k1 = (d1 >= lo) && (d1 < lo + NPX);
        unsigned int t0 = k0 ? (unsigned int)tok[s0] : 0u;   // L2-hot 200KB gather
        unsigned int t1 = k1 ? (unsigned int)tok[s1] : 0u;
        if (k0) {
            int pos = atomicAdd(&cnt[d0], 1);
            if (pos < NB) bucket[(long)d0 * NB + pos] = (unsigned int)s0 | (t0 << 16);
        }
        if (k1) {
            int pos = atomicAdd(&cnt[d1], 1);
            if (pos < NB) bucket[(long)d1 * NB + pos] = (unsigned int)s1 | (t1 << 16);
        }
        return;
    }
    gid -= SEC_E;
    if (gid < EBUF_T) {
        int t = gid >> 5, c = gid & 31;
        float2 v = ((const float2*)(embed + (long)t * HID))[c];
        ebufg[gid] = packbf(v.x, v.y);
        return;
    }
    gid -= EBUF_T;
    if (gid < N_NODES) {
        int n = gid;
        int b = batch[n];
        if (n == 0 || batch[n - 1] != b) pos_start[b] = n;
        if (n == N_NODES - 1 || batch[n + 1] != b) pos_end[b] = n + 1;
        return;
    }
    gid -= N_NODES;
    if (gid < 2 * PW_T) {
        const float* Wl = (gid < PW_T) ? W1l : W2l;
        const float* Wr = (gid < PW_T) ? W1r : W2r;
        unsigned int* wb = (gid < PW_T) ? wb1 : wb2;
        int i = (gid < PW_T) ? gid : gid - PW_T;
        int h = i >> 6, c = i & 63;   // row h: uints 0..31 = Wl, 32..63 = Wr
        float2 v = (c < 32) ? ((const float2*)(Wl + (long)h * HID))[c]
                            : ((const float2*)(Wr + (long)h * HID))[c - 32];
        wb[i] = packbf(v.x, v.y);
    }
}

// ------- fused layer, templated on nodes-per-block ----
// R9 change: Phase A restructured load-all-then-accumulate. R8's
// `if (j<m) {load; acc;}` serialized the 8 gathers (VGPR_Count=28 -> ~2 loads
// in flight -> 8x latency per row). Now: hoist 4 rows' cnt+bucket loads, then
// per row issue all 8 gather loads into w4[8] (addresses clamped to 0 for
// masked slots; row 0 always valid), then accumulate under the mask.
// ~8 independent 16B loads in flight per lane = the MLP the latency needs.
template <bool L1, int NPBT>
__global__ __launch_bounds__(NPBT * 16) void k_layer(
    const int* __restrict__ cnt, const unsigned int* __restrict__ bucket,
    const int* __restrict__ tok, const unsigned int* __restrict__ ebufg,
    const unsigned int* __restrict__ xb,
    const unsigned int* __restrict__ wb, const float* __restrict__ bl,
    unsigned short* __restrict__ xoutb,
    const int* __restrict__ batch, float* __restrict__ gacc)
{
    __shared__ unsigned int As[NPBT * AST];
    __shared__ unsigned int elds[L1 ? 128 * EST : 1];
    const int tid  = threadIdx.x;
    const int wv   = tid >> 6;        // 0..NPBT/4-1
    const int lane = tid & 63;
    const int n0   = blockIdx.x * NPBT;

    if (L1) {
        for (int i = tid; i < EBUF_T; i += NPBT * 16) {
            int t = i >> 5, c = i & 31;
            elds[t * EST + c] = ebufg[i];
        }
        __syncthreads();
    }

    const int q  = lane & 7;          // 16B chunk (channels 8q..8q+7)
    const int e8 = lane >> 3;         // edge slot within group of 8

    // ---- hoisted row state: 4x cnt + 4x bucket loads issued up-front ----
    int degA[4]; unsigned int vA[4]; int mA[4]; int ncA[4];
#pragma unroll
    for (int i = 0; i < 4; ++i) {
        int nn = n0 + wv * 4 + i;
        int nc = min(nn, N_NODES - 1);
        ncA[i] = nc;
        degA[i] = cnt[nc];                          // load (independent)
        vA[i] = bucket[(long)nc * NB + lane];       // load, unconditional (NB slots)
    }
#pragma unroll
    for (int i = 0; i < 4; ++i) {
        int nn = n0 + wv * 4 + i;
        mA[i] = (nn < N_NODES) ? min(degA[i], NB) : 0;
    }

#pragma unroll
    for (int i = 0; i < 4; ++i) {
        int rl = wv * 4 + i;          // local row 0..NPBT-1
        int m  = mA[i];
        // ---- issue all 8 gathers first (static-indexed reg array) ----
        uint4 w4[8];
#pragma unroll
        for (int g = 0; g < 8; ++g) {
            int j = g * 8 + e8;
            unsigned int vv = __shfl(vA[i], j, 64);
            vv = (j < m) ? vv : 0u;                 // clamp addr for masked slots
            if (L1) w4[g] = *(const uint4*)(elds + (vv >> 16) * EST + q * 4);
            else    w4[g] = *((const uint4*)(xb + (long)(vv & 0xffffu) * 32) + q);
        }
        // ---- accumulate under mask ----
        float f0 = 0, f1 = 0, f2 = 0, f3 = 0, f4 = 0, f5 = 0, f6 = 0, f7 = 0;
#pragma unroll
        for (int g = 0; g < 8; ++g) {
            int j = g * 8 + e8;
            if (j < m) {
                f0 += bf2f(w4[g].x & 0xffff); f1 += bf2f(w4[g].x >> 16);
                f2 += bf2f(w4[g].y & 0xffff); f3 += bf2f(w4[g].y >> 16);
                f4 += bf2f(w4[g].z & 0xffff); f5 += bf2f(w4[g].z >> 16);
                f6 += bf2f(w4[g].w & 0xffff); f7 += bf2f(w4[g].w >> 16);
            }
        }
#pragma unroll
        for (int o = 8; o < 64; o <<= 1) {
            f0 += __shfl_xor(f0, o, 64); f1 += __shfl_xor(f1, o, 64);
            f2 += __shfl_xor(f2, o, 64); f3 += __shfl_xor(f3, o, 64);
            f4 += __shfl_xor(f4, o, 64); f5 += __shfl_xor(f5, o, 64);
            f6 += __shfl_xor(f6, o, 64); f7 += __shfl_xor(f7, o, 64);
        }
        if (e8 == 0) {
            float inv = 1.0f / (float)max(degA[i], 1);
            uint4 o;
            o.x = packbf(f0 * inv, f1 * inv);
            o.y = packbf(f2 * inv, f3 * inv);
            o.z = packbf(f4 * inv, f5 * inv);
            o.w = packbf(f6 * inv, f7 * inv);
            *(uint4*)(As + rl * AST + q * 4) = o;
        } else if (e8 == 1) {
            uint4 sv;
            if (L1) { int tk = tok[ncA[i]]; sv = *(const uint4*)(elds + tk * EST + q * 4); }
            else    { sv = *((const uint4*)(xb + (long)ncA[i] * 32) + q); }
            *(uint4*)(As + rl * AST + 32 + q * 4) = sv;
        }
    }
    __syncthreads();

    // Phase B: wave wv -> strip s (16 nodes), h-tile t (16 channels)
    constexpr int NSTR = NPBT / 16;   // strips per block (2 or 1)
    const int s    = wv % NSTR;
    const int t    = wv / NSTR;
    const int mm   = lane & 15;
    const int quad = lane >> 4;

    bf16x8 afr[4];
#pragma unroll
    for (int kst = 0; kst < 4; ++kst)
        afr[kst] = *(const bf16x8*)(As + (s * 16 + mm) * AST + kst * 16 + quad * 4);

    f32x4 acc = (f32x4){0.f, 0.f, 0.f, 0.f};
#pragma unroll
    for (int kst = 0; kst < 4; ++kst) {
        bf16x8 bfr = *(const bf16x8*)(wb + (t * 16 + mm) * 64 + kst * 16 + quad * 4);
        acc = __builtin_amdgcn_mfma_f32_16x16x32_bf16(bfr, afr[kst], acc, 0, 0, 0);
    }

    // C^T[h][node]: h = t*16 + quad*4 + r, node = n0 + s*16 + mm
    int node = n0 + s * 16 + mm;
    int hb = t * 16 + quad * 4;
    float4 bb = *(const float4*)(bl + hb);
    float a0 = fmaxf(acc[0] + bb.x, 0.f);
    float a1 = fmaxf(acc[1] + bb.y, 0.f);
    float a2 = fmaxf(acc[2] + bb.z, 0.f);
    float a3 = fmaxf(acc[3] + bb.w, 0.f);

    if constexpr (L1) {
        if (node < N_NODES) {
            ushort4 o;
            o.x = f2bf(a0); o.y = f2bf(a1); o.z = f2bf(a2); o.w = f2bf(a3);
            *(ushort4*)(xoutb + (long)node * HID + hb) = o;
        }
    } else {
        // --- pooled epilogue (N_NODES % 16 == 0 -> node always valid) ---
        int g = batch[node];
        // segmented inclusive scan over the 16 mm-lanes (g non-decreasing)
#pragma unroll
        for (int off = 1; off < 16; off <<= 1) {
            float o0 = __shfl_up(a0, off, 16), o1 = __shfl_up(a1, off, 16);
            float o2 = __shfl_up(a2, off, 16), o3 = __shfl_up(a3, off, 16);
            int   og = __shfl_up(g, off, 16);
            if (mm >= off && og == g) { a0 += o0; a1 += o1; a2 += o2; a3 += o3; }
        }
        int gn = __shfl_down(g, 1, 16);
        if (mm == 15 || gn != g) {     // segment-last lane holds the segment sum
            float* dp = gacc + g * HID + hb;
            unsafeAtomicAdd(dp + 0, a0);
            unsafeAtomicAdd(dp + 1, a1);
            unsafeAtomicAdd(dp + 2, a2);
            unsafeAtomicAdd(dp + 3, a3);
        }
    }
}

// ------- head micro-kernel: out[g] = (gacc[g]/count[g]) @ Wlin^T + blin -------
__global__ __launch_bounds__(256) void k_head(
    const float* __restrict__ gacc,
    const int* __restrict__ pstart, const int* __restrict__ pend,
    const float* __restrict__ Wlin, const float* __restrict__ blin,
    float* __restrict__ out)
{
    int g = blockIdx.x * blockDim.x + threadIdx.x;
    if (g >= N_GRAPHS) return;
    float inv = 1.0f / (float)max(pend[g] - pstart[g], 1);
    float s0 = 0, s1 = 0, s2 = 0, s3 = 0, s4 = 0;
    const float* row = gacc + g * HID;
#pragma unroll 8
    for (int k = 0; k < HID; ++k) {
        float mk = row[k] * inv;
        s0 += mk * Wlin[0 * HID + k];
        s1 += mk * Wlin[1 * HID + k];
        s2 += mk * Wlin[2 * HID + k];
        s3 += mk * Wlin[3 * HID + k];
        s4 += mk * Wlin[4 * HID + k];
    }
    out[g * NCLS + 0] = s0 + blin[0];
    out[g * NCLS + 1] = s1 + blin[1];
    out[g * NCLS + 2] = s2 + blin[2];
    out[g * NCLS + 3] = s3 + blin[3];
    out[g * NCLS + 4] = s4 + blin[4];
}

extern "C" void kernel_launch(void* const* d_in, const int* in_sizes, int n_in,
                              void* d_out, int out_size, void* d_ws, size_t ws_size,
                              hipStream_t stream) {
    const int*   tok   = (const int*)d_in[0];
    const int*   eidx  = (const int*)d_in[1];
    const int*   batch = (const int*)d_in[2];
    const float* embed = (const float*)d_in[3];
    const float* W1l   = (const float*)d_in[4];
    const float* b1l   = (const float*)d_in[5];
    const float* W1r   = (const float*)d_in[6];
    const float* W2l   = (const float*)d_in[7];
    const float* b2l   = (const float*)d_in[8];
    const float* W2r   = (const float*)d_in[9];
    const float* Wlin  = (const float*)d_in[10];
    const float* blin  = (const float*)d_in[11];
    float* out = (float*)d_out;

    const int* src = eidx;
    const int* dst = eidx + N_EDGES;

    char* wsp = (char*)d_ws;
    size_t off = 0;
    auto alloc = [&](size_t bytes) -> void* {
        void* p = wsp + off;
        off = (off + bytes + 255) & ~(size_t)255;
        return p;
    };
    // cnt | pstart | pend | gacc adjacent -> single memset
    int*   cnt     = (int*)  alloc((size_t)N_NODES * 4);
    int*   pstart  = (int*)  alloc((size_t)N_GRAPHS * 4);
    int*   pend    = (int*)  alloc((size_t)N_GRAPHS * 4);
    float* gacc    = (float*)alloc((size_t)N_GRAPHS * HID * 4);
    unsigned int* bucket = (unsigned int*)alloc((size_t)N_NODES * NB * 4);
    unsigned int* x1b    = (unsigned int*)alloc((size_t)N_NODES * 32 * 4);
    unsigned int* ebufg  = (unsigned int*)alloc((size_t)128 * 32 * 4);
    unsigned int* wb1    = (unsigned int*)alloc((size_t)64 * 64 * 4);
    unsigned int* wb2    = (unsigned int*)alloc((size_t)64 * 64 * 4);

    hipMemsetAsync(cnt, 0, ((char*)gacc + (size_t)N_GRAPHS * HID * 4) - (char*)cnt, stream);

    k_prep_fill<<<(PREP_T + 255) / 256, 256, 0, stream>>>(
        src, dst, tok, cnt, bucket,
        embed, ebufg, batch, pstart, pend, W1l, W1r, wb1, W2l, W2r, wb2);

    // Layer 1: neighbors+self from LDS embed table; 32 nodes / 512-thr block
    k_layer<true, 32><<<(N_NODES + 31) / 32, 512, 0, stream>>>(
        cnt, bucket, tok, ebufg, nullptr, wb1, b1l, (unsigned short*)x1b,
        nullptr, nullptr);
    // Layer 2 + pooled epilogue: 16 nodes / 256-thr block
    k_layer<false, 16><<<N_NODES / 16, 256, 0, stream>>>(
        cnt, bucket, nullptr, nullptr, x1b, wb2, b2l, nullptr,
        batch, gacc);

    // Head (kernel boundary = ordering + cross-XCD coherence for gacc atomics)
    k_head<<<(N_GRAPHS + 255) / 256, 256, 0, stream>>>(
        gacc, pstart, pend, Wlin, blin, out);
}

// Round 10
// 184.998 us; speedup vs baseline: 1.0338x; 1.0338x over previous
//
#include <hip/hip_runtime.h>

#define N_NODES  50000
#define N_EDGES  800000
#define N_GRAPHS 512
#define HID      64
#define NCLS     5
#define NB       64      // bucket capacity per node (max deg ~40 for this graph)
#define EST      36      // LDS table row stride in uints (36%8!=0 spreads banks; 144B keeps 16B align)
#define AST      68      // LDS As row stride in uints (64 data + 4 pad)

typedef __attribute__((ext_vector_type(8))) short bf16x8;
typedef __attribute__((ext_vector_type(4))) float f32x4;

__device__ inline unsigned short f2bf(float f) {
    unsigned int u = __builtin_bit_cast(unsigned int, f);
    unsigned int r = (u + 0x7FFFu + ((u >> 16) & 1u)) >> 16;   // RNE
    return (unsigned short)r;
}
__device__ inline unsigned int packbf(float a, float b) {
    return (unsigned int)f2bf(a) | ((unsigned int)f2bf(b) << 16);
}
__device__ inline float bf2f(unsigned int u16) {
    unsigned int t = u16 << 16;
    return __builtin_bit_cast(float, t);
}

// ------- merged prep+fill -------
// Edge section: R6 form (8x XCD-range replication, 2-edge ILP).
// NEW (R10): instead of packing embed/W1, compute the folded layer-1 tables
//   E1l = embed @ W1l^T,  E1r = embed @ W1r^T   (each 128x64, bf16-packed)
// Layer 1 is then a pure gather-mean from E1l plus an E1r row lookup — its
// MFMA/As/self-staging phase is deleted entirely (linearity of SAGE conv).
#define XCDS   8
#define NPX    (N_NODES / XCDS)                     // 6250, exact
#define EPB    512                                  // edges per chunk
#define ECH2   ((N_EDGES + EPB - 1) / EPB)          // 1563 chunks
#define SEC_E  (ECH2 * XCDS * 256)                  // 3,201,024 threads
#define E_T    (2 * 128 * 32)                       // 8192: E1l | E1r packed uints
#define PW_T   (64 * 64)                            // 4096: wb2 pack
#define PREP_T (SEC_E + E_T + N_NODES + PW_T)
__global__ void k_prep_fill(
    const int* __restrict__ src, const int* __restrict__ dst,
    const int* __restrict__ tok,
    int* __restrict__ cnt, unsigned int* __restrict__ bucket,
    const float* __restrict__ embed,
    const float* __restrict__ W1l, const float* __restrict__ W1r,
    unsigned int* __restrict__ e1g,
    const int* __restrict__ batch,
    int* __restrict__ pos_start, int* __restrict__ pos_end,
    const float* __restrict__ W2l, const float* __restrict__ W2r,
    unsigned int* __restrict__ wb2) {
    int gid = blockIdx.x * blockDim.x + threadIdx.x;
    if (gid < SEC_E) {
        int blk   = gid >> 8;          // == blockIdx.x within this section
        int tidl  = gid & 255;
        int range = blk & 7;           // XCD slot (round-robin heuristic)
        int chunk = blk >> 3;          // 0..1562
        int lo = range * NPX;
        int e0 = chunk * EPB + tidl;
        int e1 = e0 + 256;
        int d0 = (e0 < N_EDGES) ? dst[e0] : -1;
        int d1 = (e1 < N_EDGES) ? dst[e1] : -1;
        int s0 = (e0 < N_EDGES) ? src[e0] : 0;
        int s1 = (e1 < N_EDGES) ? src[e1] : 0;
        bool k0 = (d0 >= lo) && (d0 < lo + NPX);
        bool k1 = (d1 >= lo) && (d1 < lo + NPX);
        unsigned int t0 = k0 ? (unsigned int)tok[s0] : 0u;   // L2-hot 200KB gather
        unsigned int t1 = k1 ? (unsigned int)tok[s1] : 0u;
        if (k0) {
            int pos = atomicAdd(&cnt[d0], 1);
            if (pos < NB) bucket[(long)d0 * NB + pos] = (unsigned int)s0 | (t0 << 16);
        }
        if (k1) {
            int pos = atomicAdd(&cnt[d1], 1);
            if (pos < NB) bucket[(long)d1 * NB + pos] = (unsigned int)s1 | (t1 << 16);
        }
        return;
    }
    gid -= SEC_E;
    if (gid < E_T) {
        // e1g[0..4095] = E1l packed, e1g[4096..8191] = E1r packed
        int idx = gid & 4095;
        int t = idx >> 5, c = idx & 31;       // token row t, channels 2c, 2c+1
        const float* W = (gid < 4096) ? W1l : W1r;
        const float* e  = embed + (long)t * HID;
        const float* w0 = W + (long)(2 * c) * HID;
        const float* w1 = w0 + HID;
        float a0 = 0.f, a1 = 0.f;
#pragma unroll 8
        for (int k = 0; k < HID; ++k) {
            float ev = e[k];
            a0 += ev * w0[k];
            a1 += ev * w1[k];
        }
        e1g[gid] = packbf(a0, a1);
        return;
    }
    gid -= E_T;
    if (gid < N_NODES) {
        int n = gid;
        int b = batch[n];
        if (n == 0 || batch[n - 1] != b) pos_start[b] = n;
        if (n == N_NODES - 1 || batch[n + 1] != b) pos_end[b] = n + 1;
        return;
    }
    gid -= N_NODES;
    if (gid < PW_T) {
        int h = gid >> 6, c = gid & 63;   // row h: uints 0..31 = W2l, 32..63 = W2r
        float2 v = (c < 32) ? ((const float2*)(W2l + (long)h * HID))[c]
                            : ((const float2*)(W2r + (long)h * HID))[c - 32];
        wb2[gid] = packbf(v.x, v.y);
    }
}

// ------- layer 1 (folded): gather-mean from E1l + E1r[tok_self] + b1l -> x1b ----
// No MFMA phase, no As tile, no second barrier: out row is produced directly
// by the reduce. 512 thr = 8 waves = 32 nodes/block (4 rows/wave).
__global__ __launch_bounds__(512) void k_layer1(
    const int* __restrict__ cnt, const unsigned int* __restrict__ bucket,
    const int* __restrict__ tok, const unsigned int* __restrict__ e1g,
    const float* __restrict__ bl, unsigned int* __restrict__ x1b)
{
    __shared__ unsigned int el[128 * EST];   // E1l, 18432 B
    __shared__ unsigned int er[128 * EST];   // E1r, 18432 B
    const int tid  = threadIdx.x;
    const int wv   = tid >> 6;        // 0..7
    const int lane = tid & 63;
    const int n0   = blockIdx.x * 32;

    for (int i = tid; i < 4096; i += 512) {
        int t = i >> 5, c = i & 31;
        el[t * EST + c] = e1g[i];
        er[t * EST + c] = e1g[4096 + i];
    }
    __syncthreads();

    const int q  = lane & 7;          // 16B chunk (channels 8q..8q+7)
    const int e8 = lane >> 3;         // edge slot within group of 8

    // hoisted per-row loads (4x cnt + 4x bucket + 4x tok in flight)
    int degA[4]; unsigned int vA[4]; int tkA[4];
#pragma unroll
    for (int i = 0; i < 4; ++i) {
        int nn = n0 + wv * 4 + i;
        int nc = min(nn, N_NODES - 1);
        degA[i] = cnt[nc];
        vA[i]   = bucket[(long)nc * NB + lane];
        tkA[i]  = tok[nc];
    }

#pragma unroll
    for (int i = 0; i < 4; ++i) {
        int nn = n0 + wv * 4 + i;
        int m  = (nn < N_NODES) ? min(degA[i], NB) : 0;
        float f0 = 0, f1 = 0, f2 = 0, f3 = 0, f4 = 0, f5 = 0, f6 = 0, f7 = 0;
#pragma unroll
        for (int g = 0; g < 8; ++g) {
            int j = g * 8 + e8;
            unsigned int vv = __shfl(vA[i], j, 64);
            if (j < m) {   // LDS gather: conditional skip saves bank bandwidth
                uint4 w4 = *(const uint4*)(el + (vv >> 16) * EST + q * 4);
                f0 += bf2f(w4.x & 0xffff); f1 += bf2f(w4.x >> 16);
                f2 += bf2f(w4.y & 0xffff); f3 += bf2f(w4.y >> 16);
                f4 += bf2f(w4.z & 0xffff); f5 += bf2f(w4.z >> 16);
                f6 += bf2f(w4.w & 0xffff); f7 += bf2f(w4.w >> 16);
            }
        }
#pragma unroll
        for (int o = 8; o < 64; o <<= 1) {
            f0 += __shfl_xor(f0, o, 64); f1 += __shfl_xor(f1, o, 64);
            f2 += __shfl_xor(f2, o, 64); f3 += __shfl_xor(f3, o, 64);
            f4 += __shfl_xor(f4, o, 64); f5 += __shfl_xor(f5, o, 64);
            f6 += __shfl_xor(f6, o, 64); f7 += __shfl_xor(f7, o, 64);
        }
        if (e8 == 0 && nn < N_NODES) {
            float inv = 1.0f / (float)max(degA[i], 1);
            uint4 sv = *(const uint4*)(er + tkA[i] * EST + q * 4);
            float4 b0 = *(const float4*)(bl + q * 8);
            float4 b1 = *(const float4*)(bl + q * 8 + 4);
            uint4 o;
            o.x = packbf(fmaxf(f0 * inv + bf2f(sv.x & 0xffff) + b0.x, 0.f),
                         fmaxf(f1 * inv + bf2f(sv.x >> 16)    + b0.y, 0.f));
            o.y = packbf(fmaxf(f2 * inv + bf2f(sv.y & 0xffff) + b0.z, 0.f),
                         fmaxf(f3 * inv + bf2f(sv.y >> 16)    + b0.w, 0.f));
            o.z = packbf(fmaxf(f4 * inv + bf2f(sv.z & 0xffff) + b1.x, 0.f),
                         fmaxf(f5 * inv + bf2f(sv.z >> 16)    + b1.y, 0.f));
            o.w = packbf(fmaxf(f6 * inv + bf2f(sv.w & 0xffff) + b1.z, 0.f),
                         fmaxf(f7 * inv + bf2f(sv.w >> 16)    + b1.w, 0.f));
            *(uint4*)(x1b + (long)nn * 32 + q * 4) = o;
        }
    }
}

// ------- layer 2 + pooled epilogue (R9 structure, 16 nodes / 256 thr) ----
__global__ __launch_bounds__(256) void k_layer2(
    const int* __restrict__ cnt, const unsigned int* __restrict__ bucket,
    const unsigned int* __restrict__ xb,
    const unsigned int* __restrict__ wb, const float* __restrict__ bl,
    const int* __restrict__ batch, float* __restrict__ gacc)
{
    __shared__ unsigned int As[16 * AST];
    const int tid  = threadIdx.x;
    const int wv   = tid >> 6;        // 0..3
    const int lane = tid & 63;
    const int n0   = blockIdx.x * 16;

    const int q  = lane & 7;
    const int e8 = lane >> 3;

    // hoisted row loads
    int degA[4]; unsigned int vA[4]; int mA[4]; int ncA[4];
#pragma unroll
    for (int i = 0; i < 4; ++i) {
        int nn = n0 + wv * 4 + i;
        int nc = min(nn, N_NODES - 1);
        ncA[i] = nc;
        degA[i] = cnt[nc];
        vA[i] = bucket[(long)nc * NB + lane];
    }
#pragma unroll
    for (int i = 0; i < 4; ++i) {
        int nn = n0 + wv * 4 + i;
        mA[i] = (nn < N_NODES) ? min(degA[i], NB) : 0;
    }

#pragma unroll
    for (int i = 0; i < 4; ++i) {
        int rl = wv * 4 + i;
        int m  = mA[i];
        uint4 w4[8];
#pragma unroll
        for (int g = 0; g < 8; ++g) {
            int j = g * 8 + e8;
            unsigned int vv = __shfl(vA[i], j, 64);
            vv = (j < m) ? vv : 0u;                 // clamp addr for masked slots
            w4[g] = *((const uint4*)(xb + (long)(vv & 0xffffu) * 32) + q);
        }
        float f0 = 0, f1 = 0, f2 = 0, f3 = 0, f4 = 0, f5 = 0, f6 = 0, f7 = 0;
#pragma unroll
        for (int g = 0; g < 8; ++g) {
            int j = g * 8 + e8;
            if (j < m) {
                f0 += bf2f(w4[g].x & 0xffff); f1 += bf2f(w4[g].x >> 16);
                f2 += bf2f(w4[g].y & 0xffff); f3 += bf2f(w4[g].y >> 16);
                f4 += bf2f(w4[g].z & 0xffff); f5 += bf2f(w4[g].z >> 16);
                f6 += bf2f(w4[g].w & 0xffff); f7 += bf2f(w4[g].w >> 16);
            }
        }
#pragma unroll
        for (int o = 8; o < 64; o <<= 1) {
            f0 += __shfl_xor(f0, o, 64); f1 += __shfl_xor(f1, o, 64);
            f2 += __shfl_xor(f2, o, 64); f3 += __shfl_xor(f3, o, 64);
            f4 += __shfl_xor(f4, o, 64); f5 += __shfl_xor(f5, o, 64);
            f6 += __shfl_xor(f6, o, 64); f7 += __shfl_xor(f7, o, 64);
        }
        if (e8 == 0) {
            float inv = 1.0f / (float)max(degA[i], 1);
            uint4 o;
            o.x = packbf(f0 * inv, f1 * inv);
            o.y = packbf(f2 * inv, f3 * inv);
            o.z = packbf(f4 * inv, f5 * inv);
            o.w = packbf(f6 * inv, f7 * inv);
            *(uint4*)(As + rl * AST + q * 4) = o;
        } else if (e8 == 1) {
            uint4 sv = *((const uint4*)(xb + (long)ncA[i] * 32) + q);
            *(uint4*)(As + rl * AST + 32 + q * 4) = sv;
        }
    }
    __syncthreads();

    // Phase B: wave wv -> h-tile t = wv (block strip = its 16 nodes)
    const int t    = wv;
    const int mm   = lane & 15;
    const int quad = lane >> 4;

    bf16x8 afr[4];
#pragma unroll
    for (int kst = 0; kst < 4; ++kst)
        afr[kst] = *(const bf16x8*)(As + mm * AST + kst * 16 + quad * 4);

    f32x4 acc = (f32x4){0.f, 0.f, 0.f, 0.f};
#pragma unroll
    for (int kst = 0; kst < 4; ++kst) {
        bf16x8 bfr = *(const bf16x8*)(wb + (t * 16 + mm) * 64 + kst * 16 + quad * 4);
        acc = __builtin_amdgcn_mfma_f32_16x16x32_bf16(bfr, afr[kst], acc, 0, 0, 0);
    }

    int node = n0 + mm;               // N_NODES % 16 == 0 -> always valid
    int hb = t * 16 + quad * 4;
    float4 bb = *(const float4*)(bl + hb);
    float a0 = fmaxf(acc[0] + bb.x, 0.f);
    float a1 = fmaxf(acc[1] + bb.y, 0.f);
    float a2 = fmaxf(acc[2] + bb.z, 0.f);
    float a3 = fmaxf(acc[3] + bb.w, 0.f);

    // pooled epilogue: segmented scan over sorted batch key, 1-2 atomics/segment
    int g = batch[node];
#pragma unroll
    for (int off = 1; off < 16; off <<= 1) {
        float o0 = __shfl_up(a0, off, 16), o1 = __shfl_up(a1, off, 16);
        float o2 = __shfl_up(a2, off, 16), o3 = __shfl_up(a3, off, 16);
        int   og = __shfl_up(g, off, 16);
        if (mm >= off && og == g) { a0 += o0; a1 += o1; a2 += o2; a3 += o3; }
    }
    int gn = __shfl_down(g, 1, 16);
    if (mm == 15 || gn != g) {
        float* dp = gacc + g * HID + hb;
        unsafeAtomicAdd(dp + 0, a0);
        unsafeAtomicAdd(dp + 1, a1);
        unsafeAtomicAdd(dp + 2, a2);
        unsafeAtomicAdd(dp + 3, a3);
    }
    // NO __threadfence (R7 lesson) — k_head's kernel boundary is the sync point
}

// ------- head micro-kernel: out[g] = (gacc[g]/count[g]) @ Wlin^T + blin -------
__global__ __launch_bounds__(256) void k_head(
    const float* __restrict__ gacc,
    const int* __restrict__ pstart, const int* __restrict__ pend,
    const float* __restrict__ Wlin, const float* __restrict__ blin,
    float* __restrict__ out)
{
    int g = blockIdx.x * blockDim.x + threadIdx.x;
    if (g >= N_GRAPHS) return;
    float inv = 1.0f / (float)max(pend[g] - pstart[g], 1);
    float s0 = 0, s1 = 0, s2 = 0, s3 = 0, s4 = 0;
    const float* row = gacc + g * HID;
#pragma unroll 8
    for (int k = 0; k < HID; ++k) {
        float mk = row[k] * inv;
        s0 += mk * Wlin[0 * HID + k];
        s1 += mk * Wlin[1 * HID + k];
        s2 += mk * Wlin[2 * HID + k];
        s3 += mk * Wlin[3 * HID + k];
        s4 += mk * Wlin[4 * HID + k];
    }
    out[g * NCLS + 0] = s0 + blin[0];
    out[g * NCLS + 1] = s1 + blin[1];
    out[g * NCLS + 2] = s2 + blin[2];
    out[g * NCLS + 3] = s3 + blin[3];
    out[g * NCLS + 4] = s4 + blin[4];
}

extern "C" void kernel_launch(void* const* d_in, const int* in_sizes, int n_in,
                              void* d_out, int out_size, void* d_ws, size_t ws_size,
                              hipStream_t stream) {
    const int*   tok   = (const int*)d_in[0];
    const int*   eidx  = (const int*)d_in[1];
    const int*   batch = (const int*)d_in[2];
    const float* embed = (const float*)d_in[3];
    const float* W1l   = (const float*)d_in[4];
    const float* b1l   = (const float*)d_in[5];
    const float* W1r   = (const float*)d_in[6];
    const float* W2l   = (const float*)d_in[7];
    const float* b2l   = (const float*)d_in[8];
    const float* W2r   = (const float*)d_in[9];
    const float* Wlin  = (const float*)d_in[10];
    const float* blin  = (const float*)d_in[11];
    float* out = (float*)d_out;

    const int* src = eidx;
    const int* dst = eidx + N_EDGES;

    char* wsp = (char*)d_ws;
    size_t off = 0;
    auto alloc = [&](size_t bytes) -> void* {
        void* p = wsp + off;
        off = (off + bytes + 255) & ~(size_t)255;
        return p;
    };
    // cnt | pstart | pend | gacc adjacent -> single memset
    int*   cnt     = (int*)  alloc((size_t)N_NODES * 4);
    int*   pstart  = (int*)  alloc((size_t)N_GRAPHS * 4);
    int*   pend    = (int*)  alloc((size_t)N_GRAPHS * 4);
    float* gacc    = (float*)alloc((size_t)N_GRAPHS * HID * 4);
    unsigned int* bucket = (unsigned int*)alloc((size_t)N_NODES * NB * 4);
    unsigned int* x1b    = (unsigned int*)alloc((size_t)N_NODES * 32 * 4);
    unsigned int* e1g    = (unsigned int*)alloc((size_t)E_T * 4);
    unsigned int* wb2    = (unsigned int*)alloc((size_t)PW_T * 4);

    hipMemsetAsync(cnt, 0, ((char*)gacc + (size_t)N_GRAPHS * HID * 4) - (char*)cnt, stream);

    k_prep_fill<<<(PREP_T + 255) / 256, 256, 0, stream>>>(
        src, dst, tok, cnt, bucket,
        embed, W1l, W1r, e1g, batch, pstart, pend, W2l, W2r, wb2);

    // Layer 1 (folded tables): 32 nodes / 512-thr block
    k_layer1<<<(N_NODES + 31) / 32, 512, 0, stream>>>(
        cnt, bucket, tok, e1g, b1l, x1b);
    // Layer 2 + pooled epilogue: 16 nodes / 256-thr block
    k_layer2<<<N_NODES / 16, 256, 0, stream>>>(
        cnt, bucket, x1b, wb2, b2l, batch, gacc);

    // Head (kernel boundary = ordering + cross-XCD coherence for gacc atomics)
    k_head<<<(N_GRAPHS + 255) / 256, 256, 0, stream>>>(
        gacc, pstart, pend, Wlin, blin, out);
}